// Round 9
// baseline (452.532 us; speedup 1.0000x reference)
//
#include <hip/hip_runtime.h>

typedef __attribute__((ext_vector_type(4))) float f32x4;
typedef __attribute__((ext_vector_type(8))) short s16x8;

__device__ __forceinline__ ushort f2bf(float f) {
  union { float f; uint u; } v; v.f = f;
  uint r = v.u + 0x7fffu + ((v.u >> 16) & 1u);
  return (ushort)(r >> 16);
}
__device__ __forceinline__ float bf2f(ushort u) {
  union { uint i; float f; } v; v.i = ((uint)u) << 16; return v.f;
}

// swizzled index into a [rows][256] bf16 tile (16B-chunk XOR by row&7)
__device__ __forceinline__ int asidx(int row, int col) {
  return row*256 + ((((col>>3) ^ (row & 7)))<<3) + (col&7);
}
// swizzled index into a [rows][32] bf16 scratch tile
__device__ __forceinline__ int scridx(int row, int col) {
  return row*32 + ((((col>>3) ^ ((row>>2)&3)))<<3) + (col&7);
}

struct WSrc { const float* p[8]; };

// Weights -> FRAGMENT-MAJOR bf16: for (axis a, stage st 0..31, colhalf ch),
// element [ks][lane][e] = W^T[nb + (lane&15)][ks*32 + (lane>>4)*8 + e].
// A wave's B-fragment load becomes one coalesced 1KB read per (st,ch,ks).
__global__ __launch_bounds__(256) void prep_frag(WSrc s, ushort* wsf) {
  int b = blockIdx.x;
  int a = b >> 6, rem = b & 63, st = rem >> 1, ch = rem & 1;
  const float* src; int nb;
  if (st < 24) { int m = st % 3, h = st / 3; src = s.p[a*2] + m*65536; nb = h*32 + ch*16; }
  else         { src = s.p[a*2 + 1];          nb = (st - 24)*32 + ch*16; }
  ushort* dst = wsf + a*262144 + (st*2 + ch)*4096;
  for (int w = threadIdx.x; w < 512; w += 256) {
    int lane = w & 63, llo = lane & 15, lhi = lane >> 4;
    int n = nb + llo, kb = (w >> 6)*32 + lhi*8;
#pragma unroll
    for (int e = 0; e < 8; e++)
      dst[w*8 + e] = f2bf(src[(kb + e)*256 + n]);   // W[f=k][g=n]
  }
}

template<int AXIS>
__device__ __forceinline__ int token_index(int blk, int row) {
  if (AXIS == 0) {                       // temporal: 8 seqs/block of len 8
    int seq = blk*8 + (row >> 3);
    int t = row & 7;
    int b = seq >> 12, n = seq & 4095;
    return (b*8 + t)*4096 + n;
  } else {
    int sid = blk*4 + (row >> 4);        // 4 seqs/block of len 16
    int bt = sid >> 8, lo = sid & 255, r = row & 15;
    if (AXIS == 1) { int hh = lo >> 4, ww = lo & 15; return bt*4096 + r*256 + hh*16 + ww; }
    if (AXIS == 2) { int dd = lo >> 4, ww = lo & 15; return bt*4096 + dd*256 + r*16 + ww; }
    { int dd = lo >> 4, hh = lo & 15; return bt*4096 + dd*256 + hh*16 + r; }
  }
}

// LDS-write publication fence (raw s_barrier does NOT drain ds ops).
#define PUB_BARRIER() do { \
    __builtin_amdgcn_sched_barrier(0); \
    asm volatile("s_waitcnt lgkmcnt(0)" ::: "memory"); \
    __builtin_amdgcn_sched_barrier(0); \
    __builtin_amdgcn_s_barrier(); \
    __builtin_amdgcn_sched_barrier(0); } while (0)

template<int AXIS>
__global__ __launch_bounds__(256, 3) void axial_pass(
    const float* __restrict__ x0, const ushort* __restrict__ xb,
    const ushort* __restrict__ wfrag, const float* __restrict__ bqkv,
    const float* __restrict__ bo,
    float* __restrict__ out, ushort* __restrict__ x1b) {

  // 48 KB: As [64][256] (X stage -> attn-out -> bf16 out-proj staging),
  //        Scr: per-seq Q[16][32] | K/P[16][32] | V^T[32][32, cols16..31=0]
  __shared__ ushort smem[24576];
  ushort* As  = smem;            // 16384 us
  ushort* Scr = smem + 16384;    // 4 seqs x 2048 us

  const int tid = threadIdx.x, blk = blockIdx.x;
  const int wv = tid >> 6, lane = tid & 63, llo = lane & 15, lhi = lane >> 4;
  const int rh = wv >> 1, ch = wv & 1;     // row-half (32 rows), col-half (16 cols)
  const f32x4 fzero = {0.f, 0.f, 0.f, 0.f};
  const s16x8 szero = {0,0,0,0,0,0,0,0};
  const s16x8* wf = (const s16x8*)wfrag;   // fragment stream, s16x8 units

  // ---- stage X tile into As (swizzled) ----
  {
    int row = tid >> 2, q = tid & 3;
    int tok = token_index<AXIS>(blk, row);
    if (AXIS == 0) {
      const float4* s4 = (const float4*)(x0 + (size_t)tok*256 + q*64);
#pragma unroll
      for (int c2 = 0; c2 < 8; c2++) {
        float4 v0 = s4[c2*2], v1 = s4[c2*2 + 1];
        s16x8 o;
        o[0] = (short)f2bf(v0.x); o[1] = (short)f2bf(v0.y);
        o[2] = (short)f2bf(v0.z); o[3] = (short)f2bf(v0.w);
        o[4] = (short)f2bf(v1.x); o[5] = (short)f2bf(v1.y);
        o[6] = (short)f2bf(v1.z); o[7] = (short)f2bf(v1.w);
        *(s16x8*)(As + asidx(row, (q*8 + c2)*8)) = o;
      }
    } else {
      const s16x8* s8 = (const s16x8*)(xb + (size_t)tok*256 + q*64);
#pragma unroll
      for (int c2 = 0; c2 < 8; c2++)
        *(s16x8*)(As + asidx(row, (q*8 + c2)*8)) = s8[c2];
    }
  }
  // zero own seq's V^T k-pad (cols 16..31) once
  {
    ushort* Vtw = Scr + wv*2048 + 1024;
    *(s16x8*)(Vtw + scridx(lane >> 1, 16 + (lane & 1)*8)) = szero;
  }
  __syncthreads();   // X + pad published

  // ---- A-fragments: 2 row-groups in registers (reused for all qkv stages) ----
  s16x8 af[2][8];
#pragma unroll
  for (int rg = 0; rg < 2; rg++)
#pragma unroll
    for (int ks = 0; ks < 8; ks++)
      af[rg][ks] = *(const s16x8*)(As + asidx(rh*32 + rg*16 + llo, (ks*4 + lhi)*8));

  auto loadB = [&](int s, s16x8* bb) {
    const s16x8* p = wf + (s*2 + ch)*512 + lane;
#pragma unroll
    for (int ks = 0; ks < 8; ks++) bb[ks] = p[ks*64];
  };
  auto proj2 = [&](const s16x8* bb, f32x4& c0, f32x4& c1) {
    __builtin_amdgcn_s_setprio(1);
#pragma unroll
    for (int ks = 0; ks < 8; ks++) {
      c0 = __builtin_amdgcn_mfma_f32_16x16x32_bf16(af[0][ks], bb[ks], c0, 0, 0, 0);
      c1 = __builtin_amdgcn_mfma_f32_16x16x32_bf16(af[1][ks], bb[ks], c1, 0, 0, 0);
    }
    __builtin_amdgcn_s_setprio(0);
  };

  s16x8 bb[8];
  // ================= head loop =================
#pragma unroll 1
  for (int h = 0; h < 8; h++) {
    { // ---- Q (stage 3h) ----
      loadB(3*h, bb);
      f32x4 c0 = fzero, c1 = fzero;
      proj2(bb, c0, c1);
      float bi = bqkv[h*32 + ch*16 + llo];
#pragma unroll
      for (int r = 0; r < 4; r++) {
        (Scr + (rh*2 + 0)*2048)[scridx(lhi*4 + r, ch*16 + llo)] = f2bf(c0[r] + bi);
        (Scr + (rh*2 + 1)*2048)[scridx(lhi*4 + r, ch*16 + llo)] = f2bf(c1[r] + bi);
      }
    }
    { // ---- K (stage 3h+1) ----
      loadB(3*h + 1, bb);
      f32x4 c0 = fzero, c1 = fzero;
      proj2(bb, c0, c1);
      float bi = bqkv[256 + h*32 + ch*16 + llo];
#pragma unroll
      for (int r = 0; r < 4; r++) {
        (Scr + (rh*2 + 0)*2048 + 512)[scridx(lhi*4 + r, ch*16 + llo)] = f2bf(c0[r] + bi);
        (Scr + (rh*2 + 1)*2048 + 512)[scridx(lhi*4 + r, ch*16 + llo)] = f2bf(c1[r] + bi);
      }
    }
    { // ---- V (stage 3h+2), stored transposed [d][t] ----
      loadB(3*h + 2, bb);
      f32x4 c0 = fzero, c1 = fzero;
      proj2(bb, c0, c1);
      float bi = bqkv[512 + h*32 + ch*16 + llo];
#pragma unroll
      for (int r = 0; r < 4; r++) {
        (Scr + (rh*2 + 0)*2048 + 1024)[scridx(ch*16 + llo, lhi*4 + r)] = f2bf(c0[r] + bi);
        (Scr + (rh*2 + 1)*2048 + 1024)[scridx(ch*16 + llo, lhi*4 + r)] = f2bf(c1[r] + bi);
      }
    }
    PUB_BARRIER();   // Q,K,V for all seqs published

    { // ---- attention: this wave owns sequence wv ----
      ushort* S = Scr + wv*2048;
      s16x8 aq = *(const s16x8*)(S + scridx(llo, lhi*8));
      s16x8 bk = *(const s16x8*)(S + 512 + scridx(llo, lhi*8));
      f32x4 sc = __builtin_amdgcn_mfma_f32_16x16x32_bf16(aq, bk, fzero, 0, 0, 0);
#pragma unroll
      for (int r = 0; r < 4; r++) {
        float sv = sc[r] * 0.17677669529663689f;
        if (AXIS == 0) {   // two packed length-8 seqs: block-diagonal mask
          int srow = lhi*4 + r;
          if ((srow >> 3) != (llo >> 3)) sv = -1e30f;
        }
        float mx = sv;
        mx = fmaxf(mx, __shfl_xor(mx, 1));
        mx = fmaxf(mx, __shfl_xor(mx, 2));
        mx = fmaxf(mx, __shfl_xor(mx, 4));
        mx = fmaxf(mx, __shfl_xor(mx, 8));
        float e = __expf(sv - mx);
        float sm = e;
        sm += __shfl_xor(sm, 1);
        sm += __shfl_xor(sm, 2);
        sm += __shfl_xor(sm, 4);
        sm += __shfl_xor(sm, 8);
        (S + 512)[scridx(lhi*4 + r, llo)] = f2bf(e * __builtin_amdgcn_rcpf(sm)); // P over K
      }
      // PV (P k-pad garbage x V^T zero-pad = 0); same-wave in-order LDS
      s16x8 ap  = *(const s16x8*)(S + 512 + scridx(llo, lhi*8));
      s16x8 bv0 = *(const s16x8*)(S + 1024 + scridx(llo, lhi*8));
      s16x8 bv1 = *(const s16x8*)(S + 1024 + scridx(16 + llo, lhi*8));
      f32x4 o0 = __builtin_amdgcn_mfma_f32_16x16x32_bf16(ap, bv0, fzero, 0, 0, 0);
      f32x4 o1 = __builtin_amdgcn_mfma_f32_16x16x32_bf16(ap, bv1, fzero, 0, 0, 0);
#pragma unroll
      for (int r = 0; r < 4; r++) {
        As[asidx(wv*16 + lhi*4 + r, h*32 + llo)]      = f2bf(o0[r]);
        As[asidx(wv*16 + lhi*4 + r, h*32 + 16 + llo)] = f2bf(o1[r]);
      }
    }
    PUB_BARRIER();   // attention reads done before next head overwrites Q/K/V
  }

  // ================= out-proj: stages 24..31 =================
  // reload A-fragments = attn outputs (As published by h=7's end barrier)
#pragma unroll
  for (int rg = 0; rg < 2; rg++)
#pragma unroll
    for (int ks = 0; ks < 8; ks++)
      af[rg][ks] = *(const s16x8*)(As + asidx(rh*32 + rg*16 + llo, (ks*4 + lhi)*8));
  PUB_BARRIER();     // all waves' reloads drained before As is overwritten

#pragma unroll 1
  for (int st = 0; st < 8; st++) {
    loadB(24 + st, bb);
    f32x4 c0 = fzero, c1 = fzero;
    proj2(bb, c0, c1);
#pragma unroll
    for (int r = 0; r < 4; r++) {   // stage result as bf16 into dead As tile
      As[asidx(rh*32 + 0*16 + lhi*4 + r, st*32 + ch*16 + llo)] = f2bf(c0[r]);
      As[asidx(rh*32 + 1*16 + lhi*4 + r, st*32 + ch*16 + llo)] = f2bf(c1[r]);
    }
  }
  PUB_BARRIER();     // out-proj tile published

  // ======== vectorized epilogue: +bo, residual, float4 RMW ========
  {
    int row = tid >> 2, cg = tid & 3;
    int tok = token_index<AXIS>(blk, row);
    size_t base = (size_t)tok*256;
#pragma unroll
    for (int i = 0; i < 8; i++) {
      int col = cg*64 + i*8;
      s16x8 v8 = *(const s16x8*)(As + asidx(row, col));
      float f[8];
#pragma unroll
      for (int j = 0; j < 8; j++) f[j] = bf2f((ushort)v8[j]) + bo[col + j];
      if (AXIS == 0) {
        float4 xa = *(const float4*)&x0[base + col];
        float4 xb4 = *(const float4*)&x0[base + col + 4];
        float4 va = {f[0]+xa.x, f[1]+xa.y, f[2]+xa.z, f[3]+xa.w};
        float4 vb = {f[4]+xb4.x, f[5]+xb4.y, f[6]+xb4.z, f[7]+xb4.w};
        *(float4*)&out[base + col]     = va;
        *(float4*)&out[base + col + 4] = vb;
        ushort4 pa, pb;
        pa.x = f2bf(va.x); pa.y = f2bf(va.y); pa.z = f2bf(va.z); pa.w = f2bf(va.w);
        pb.x = f2bf(vb.x); pb.y = f2bf(vb.y); pb.z = f2bf(vb.z); pb.w = f2bf(vb.w);
        *(ushort4*)&x1b[base + col]     = pa;
        *(ushort4*)&x1b[base + col + 4] = pb;
      } else {
        float4 oa = *(float4*)&out[base + col];
        float4 ob = *(float4*)&out[base + col + 4];
        oa.x += f[0]; oa.y += f[1]; oa.z += f[2]; oa.w += f[3];
        ob.x += f[4]; ob.y += f[5]; ob.z += f[6]; ob.w += f[7];
        *(float4*)&out[base + col]     = oa;
        *(float4*)&out[base + col + 4] = ob;
      }
    }
  }
}

extern "C" void kernel_launch(void* const* d_in, const int* in_sizes, int n_in,
                              void* d_out, int out_size, void* d_ws, size_t ws_size,
                              hipStream_t stream) {
  const float* x = (const float*)d_in[0];
  ushort* wsf = (ushort*)d_ws;                 // 4 axes x 262144 us fragment buffers
  ushort* x1b = wsf + 4*262144;                // 65536*256 bf16
  float* out = (float*)d_out;

  WSrc wsrc;
  wsrc.p[0] = (const float*)d_in[1];  wsrc.p[1] = (const float*)d_in[3];
  wsrc.p[2] = (const float*)d_in[5];  wsrc.p[3] = (const float*)d_in[7];
  wsrc.p[4] = (const float*)d_in[9];  wsrc.p[5] = (const float*)d_in[11];
  wsrc.p[6] = (const float*)d_in[13]; wsrc.p[7] = (const float*)d_in[15];
  prep_frag<<<dim3(256), dim3(256), 0, stream>>>(wsrc, wsf);

  const float* bq_t = (const float*)d_in[2];  const float* bo_t = (const float*)d_in[4];
  const float* bq_d = (const float*)d_in[6];  const float* bo_d = (const float*)d_in[8];
  const float* bq_h = (const float*)d_in[10]; const float* bo_h = (const float*)d_in[12];
  const float* bq_w = (const float*)d_in[14]; const float* bo_w = (const float*)d_in[16];

  axial_pass<0><<<dim3(1024), dim3(256), 0, stream>>>(x, nullptr, wsf + 0*262144, bq_t, bo_t, out, x1b);
  axial_pass<1><<<dim3(1024), dim3(256), 0, stream>>>(nullptr, x1b, wsf + 1*262144, bq_d, bo_d, out, nullptr);
  axial_pass<2><<<dim3(1024), dim3(256), 0, stream>>>(nullptr, x1b, wsf + 2*262144, bq_h, bo_h, out, nullptr);
  axial_pass<3><<<dim3(1024), dim3(256), 0, stream>>>(nullptr, x1b, wsf + 3*262144, bq_w, bo_w, out, nullptr);
}